// Round 21
// baseline (923.226 us; speedup 1.0000x reference)
//
#include <hip/hip_runtime.h>
#include <hip/hip_bf16.h>

#define T_TOK 8192
#define D_DIM 1024
#define H_DIM 4096
#define E_NUM 8
#define IDXST 8448        // per-expert idx/wc stride (8192 + pad)
#define CAPBLK 18         // max 256-row blocks per expert (4608 rows)
#define CAPROWS (CAPBLK * 256)

typedef short bf16x8 __attribute__((ext_vector_type(8)));
typedef float f32x4 __attribute__((ext_vector_type(4)));

__device__ __forceinline__ unsigned short f2bf(float f) {
    union { float f; unsigned int u; } v; v.f = f;
    unsigned int u = v.u;
    u = u + 0x7FFFu + ((u >> 16) & 1u);   // round-to-nearest-even
    return (unsigned short)(u >> 16);
}

__device__ __forceinline__ void gload_lds16(const void* g, void* l) {
    __builtin_amdgcn_global_load_lds(
        (const __attribute__((address_space(1))) unsigned int*)g,
        (__attribute__((address_space(3))) unsigned int*)l,
        16, 0, 0);
}

// phase fences (rule 18 + pinned raw barrier)
#define SBAR() { __builtin_amdgcn_sched_barrier(0); __builtin_amdgcn_s_barrier(); __builtin_amdgcn_sched_barrier(0); }
#define LGKM0() { asm volatile("s_waitcnt lgkmcnt(0)" ::: "memory"); __builtin_amdgcn_sched_barrier(0); }
#define VMC3() { asm volatile("s_waitcnt vmcnt(3)" ::: "memory"); __builtin_amdgcn_sched_barrier(0); }
#define VMC0() { asm volatile("s_waitcnt vmcnt(0)" ::: "memory"); __builtin_amdgcn_sched_barrier(0); }

// runtime bijective XCD-chunked swizzle over ACTIVE set (m204): valid for lin < n
__device__ __forceinline__ int swz_rt(int lin, int n) {
    int q = n >> 3, r = n & 7;
    int xcd = lin & 7, pos = lin >> 3;
    int base = (xcd < r) ? xcd * (q + 1) : r * (q + 1) + (xcd - r) * q;
    return base + pos;
}

// merged-grid mapping: blockIdx -> (expert e, bm, bn) over active tiles; false = exit
template<int NBN>
__device__ __forceinline__ bool merged_map(const int* __restrict__ cntp,
                                           int& e, int& bm, int& bn, int& cnt_e) {
    int nbs[E_NUM], tot = 0;
    #pragma unroll
    for (int i = 0; i < E_NUM; ++i) {
        int c = cntp[i];
        int nbm = (c + 255) >> 8;
        if (nbm > CAPBLK) nbm = CAPBLK;
        nbs[i] = nbm * NBN;
        tot += nbs[i];
    }
    if ((int)blockIdx.x >= tot) return false;
    const int wg = swz_rt(blockIdx.x, tot);
    int acc = 0, loc = 0;
    e = 0;
    #pragma unroll
    for (int i = 0; i < E_NUM; ++i) {
        if (wg >= acc && wg < acc + nbs[i]) { e = i; loc = wg - acc; }
        acc += nbs[i];
    }
    bm = loc / NBN;
    bn = loc - bm * NBN;
    cnt_e = cntp[e];
    return true;
}

// ------- gating (fp64, mask-exact) + fused x->bf16 convert -------
__global__ void gate_cvt_kernel(const float* __restrict__ x, const float* __restrict__ Wg,
                                const float* __restrict__ bg, float* __restrict__ wout,
                                unsigned short* __restrict__ xb) {
    int wv = (int)((blockIdx.x * blockDim.x + threadIdx.x) >> 6);  // token id
    int lane = threadIdx.x & 63;
    if (wv >= T_TOK) return;
    const float* xr = x + (size_t)wv * D_DIM;
    unsigned short* xo = xb + (size_t)wv * D_DIM;
    double acc[E_NUM] = {0, 0, 0, 0, 0, 0, 0, 0};
    for (int i = 0; i < D_DIM / 64; ++i) {
        int d = i * 64 + lane;
        float xf = xr[d];
        xo[d] = f2bf(xf);
        double xv = (double)xf;
        const float* wr = Wg + (size_t)d * E_NUM;
        #pragma unroll
        for (int e = 0; e < E_NUM; ++e) acc[e] += xv * (double)wr[e];
    }
    #pragma unroll
    for (int e = 0; e < E_NUM; ++e) {
        double v = acc[e];
        for (int s = 32; s; s >>= 1) v += __shfl_down(v, s, 64);
        acc[e] = v;
    }
    if (lane == 0) {
        #pragma unroll
        for (int e = 0; e < E_NUM; ++e) {
            double z = acc[e] + (double)bg[e];
            float p = (float)(1.0 / (1.0 + exp(-z)));
            wout[(size_t)wv * E_NUM + e] = (p > 0.5f) ? p : 0.0f;
        }
    }
}

// ------- per-expert stable compaction: idx/wc lists + counts + inverse pos map -------
__global__ void compact_kernel(const float* __restrict__ wgt, int* __restrict__ idx,
                               float* __restrict__ wc, int* __restrict__ cnt,
                               int* __restrict__ pos) {
    const int e = blockIdx.x;
    const int tid = threadIdx.x;              // 256
    const int lane = tid & 63, wv = tid >> 6; // 4 waves
    int* idxe = idx + e * IDXST;
    float* wce = wc + e * IDXST;
    int* pose = pos + e * T_TOK;
    __shared__ int wtot[4];
    __shared__ int sbase;
    if (tid == 0) sbase = 0;
    __syncthreads();
    for (int t0 = 0; t0 < T_TOK; t0 += 256) {
        int t = t0 + tid;
        float w = wgt[(size_t)t * E_NUM + e];
        int act = (w > 0.0f) ? 1 : 0;
        unsigned long long mask = __ballot(act);
        int wpos = __popcll(mask & ((1ull << lane) - 1ull));
        if (lane == 0) wtot[wv] = __popcll(mask);
        __syncthreads();
        int off = sbase;
        for (int i = 0; i < wv; ++i) off += wtot[i];
        if (act) { idxe[off + wpos] = t; wce[off + wpos] = w; pose[t] = off + wpos + 1; }
        else pose[t] = 0;
        __syncthreads();
        if (tid == 0) sbase += wtot[0] + wtot[1] + wtot[2] + wtot[3];
        __syncthreads();
    }
    int total = sbase;
    int padded = ((total + 255) / 256) * 256;
    for (int i = total + tid; i < padded; i += 256) { idxe[i] = 0; wce[i] = 0.0f; }
    if (tid == 0) cnt[e] = total;
}

// ------- per-expert transpose+convert: in[e][R][C] fp32 -> out[e][C][R] bf16 -------
__global__ void transpose_cvt(const float* __restrict__ in, unsigned short* __restrict__ out,
                              int R, int C) {
    __shared__ unsigned short tile[64][65];
    int e = blockIdx.z;
    const float* src = in + (size_t)e * R * C;
    unsigned short* dst = out + (size_t)e * R * C;
    int c0 = blockIdx.x * 64, r0 = blockIdx.y * 64;
    int t = threadIdx.x;
    int cc = (t & 15) * 4;
    int rr = t >> 4;
    #pragma unroll
    for (int p = 0; p < 4; ++p) {
        int r = rr + p * 16;
        float4 v = *(const float4*)(src + (size_t)(r0 + r) * C + c0 + cc);
        tile[cc + 0][r] = f2bf(v.x);
        tile[cc + 1][r] = f2bf(v.y);
        tile[cc + 2][r] = f2bf(v.z);
        tile[cc + 3][r] = f2bf(v.w);
    }
    __syncthreads();
    int rr4 = (t & 15) * 4;
    int cw = t >> 4;
    #pragma unroll
    for (int p = 0; p < 4; ++p) {
        int c = cw + p * 16;
        ushort4 o;
        o.x = tile[c][rr4 + 0];
        o.y = tile[c][rr4 + 1];
        o.z = tile[c][rr4 + 2];
        o.w = tile[c][rr4 + 3];
        *(ushort4*)(dst + (size_t)(c0 + c) * R + r0 + rr4) = o;
    }
}

__global__ void zero_kernel(float4* __restrict__ p, size_t n4) {
    size_t i = (size_t)blockIdx.x * blockDim.x + threadIdx.x;
    size_t st = (size_t)gridDim.x * blockDim.x;
    for (; i < n4; i += st) p[i] = (float4){0.f, 0.f, 0.f, 0.f};
}

// ------- cross-expert reduce: out[t][d] = sum_e Oc[e][pos[e][t]-1][d] -------
__global__ void reduce_kernel(const float4* __restrict__ Oc, const int* __restrict__ pos,
                              float4* __restrict__ out) {
    const int D4 = D_DIM / 4;
    size_t i = (size_t)blockIdx.x * blockDim.x + threadIdx.x;   // over T*D/4
    int t = (int)(i / D4);
    int dv = (int)(i - (size_t)t * D4);
    f32x4 s = (f32x4){0.f, 0.f, 0.f, 0.f};
    #pragma unroll
    for (int e = 0; e < E_NUM; ++e) {
        int p = pos[e * T_TOK + t];
        if (p) {
            float4 v = Oc[((size_t)e * CAPROWS + (p - 1)) * D4 + dv];
            s[0] += v.x; s[1] += v.y; s[2] += v.z; s[3] += v.w;
        }
    }
    out[i] = (float4){s[0], s[1], s[2], s[3]};
}

__global__ void sentinel_kernel(float* out, size_t n) {
    size_t i = (size_t)blockIdx.x * blockDim.x + threadIdx.x;
    size_t st = (size_t)gridDim.x * blockDim.x;
    for (; i < n; i += st) out[i] = 12345.0f;
}

// ======== MERGED COMPACT GEMM1: 256x128, BK=32, A/B 3-buf, SINGLE-BARRIER (r20, unchanged) ========
__global__ __launch_bounds__(512, 4) void gemm1c(
    const unsigned short* __restrict__ Xb,
    const unsigned short* __restrict__ W1T,
    unsigned short* __restrict__ Hc,
    const float* __restrict__ b1,
    const int* __restrict__ idxb,
    const float* __restrict__ wcb,
    const int* __restrict__ cntp)
{
    __shared__ __align__(16) unsigned short lA[3][8192];   // 3 x 16 KB (256 x 32)
    __shared__ __align__(16) unsigned short lB[3][4096];   // 3 x  8 KB (128 x 32)  => 72 KB

    int e, bm, bn, cnt;
    if (!merged_map<H_DIM / 128>(cntp, e, bm, bn, cnt)) return;

    const int* idx = idxb + e * IDXST;
    const float* wc = wcb + e * IDXST;
    const unsigned short* Bmat = W1T + (size_t)e * H_DIM * D_DIM;
    const float* b1e = b1 + (size_t)e * H_DIM;
    unsigned short* HcE = Hc + (size_t)e * CAPROWS * H_DIM;

    const int tid = threadIdx.x;
    const int lane = tid & 63, wid = tid >> 6;
    const int wr = wid >> 1;        // 0..3  (M quarter: 64 rows)
    const int wcn = wid & 1;        // 0..1  (N half: 64 cols)
    const int fr = lane & 15, fq = lane >> 4;

    const int srow = tid >> 2;                                   // 0..127
    const int scol = (((tid & 3) ^ ((tid >> 3) & 3)) << 3);      // involution, 4 slots
    const unsigned short* Asrc0 = Xb + (size_t)idx[bm * 256 + srow] * D_DIM + scol;
    const unsigned short* Asrc1 = Xb + (size_t)idx[bm * 256 + 128 + srow] * D_DIM + scol;
    const unsigned short* Bb = Bmat + (size_t)(bn * 128 + srow) * D_DIM + scol;

    const int soff = (fq ^ ((fr >> 1) & 3)) * 8;                 // read slot (ushort)

    f32x4 acc[4][4];
    #pragma unroll
    for (int m = 0; m < 4; ++m)
        #pragma unroll
        for (int n = 0; n < 4; ++n)
            acc[m][n] = (f32x4){0.f, 0.f, 0.f, 0.f};

    bf16x8 a[4], b[4];

    auto stageA = [&](int bf, int kt) {
        gload_lds16(Asrc0 + kt * 32, &lA[bf][tid * 8]);
        gload_lds16(Asrc1 + kt * 32, &lA[bf][4096 + tid * 8]);
    };
    auto stageB = [&](int bf, int kt) {
        gload_lds16(Bb + kt * 32, &lB[bf][tid * 8]);
    };

    stageA(0, 0); stageB(0, 0);
    stageA(1, 1); stageB(1, 1);
    VMC3();
    SBAR();

    const int NT = D_DIM / 32;   // 32
    int cb = 0;
    for (int t = 0; t < NT; ++t) {
        const int nb2 = (cb + 2 >= 3) ? cb - 1 : cb + 2;   // (t+2)%3
        #pragma unroll
        for (int mm = 0; mm < 4; ++mm) {
            const int r = wr * 64 + mm * 16 + fr;
            a[mm] = *(const bf16x8*)&lA[cb][r * 32 + soff];
        }
        #pragma unroll
        for (int n = 0; n < 4; ++n) {
            const int rB = wcn * 64 + n * 16 + fr;
            b[n] = *(const bf16x8*)&lB[cb][rB * 32 + soff];
        }
        if (t + 2 < NT) { stageA(nb2, t + 2); stageB(nb2, t + 2); }   // issue early (T14)
        LGKM0();
        __builtin_amdgcn_s_setprio(1);
        #pragma unroll
        for (int mm = 0; mm < 4; ++mm)
            #pragma unroll
            for (int n = 0; n < 4; ++n)
                acc[mm][n] = __builtin_amdgcn_mfma_f32_16x16x32_bf16(a[mm], b[n], acc[mm][n], 0, 0, 0);
        __builtin_amdgcn_s_setprio(0);
        if (t < NT - 2) { VMC3(); } else { VMC0(); }
        SBAR();
        cb = (cb == 2) ? 0 : cb + 1;
    }

    #pragma unroll
    for (int m = 0; m < 4; ++m) {
        const int rbase = bm * 256 + wr * 64 + m * 16 + fq * 4;
        #pragma unroll
        for (int n = 0; n < 4; ++n) {
            const int cn = bn * 128 + wcn * 64 + n * 16 + fr;
            const float bb = b1e[cn];
            #pragma unroll
            for (int j = 0; j < 4; ++j) {
                const int r = rbase + j;
                const float w = wc[r];            // 0 for padded rows -> Hc row zero
                float v = fmaxf(acc[m][n][j] + bb, 0.0f) * w;
                HcE[(size_t)r * H_DIM + cn] = f2bf(v);
            }
        }
    }
}

// ======== MERGED COMPACT GEMM2<STORE>: 256x128, BK=32, A/B 3-buf, single-barrier ========
// STORE=0: atomic scatter to out (r20 behavior).  STORE=1: plain compact store to Oc.
template<int STORE>
__global__ __launch_bounds__(512, 4) void gemm2c(
    const unsigned short* __restrict__ Hc,
    const unsigned short* __restrict__ W2T,
    float* __restrict__ out,
    float* __restrict__ Oc,
    const float* __restrict__ b2,
    const int* __restrict__ idxb,
    const float* __restrict__ wcb,
    const int* __restrict__ cntp)
{
    __shared__ __align__(16) unsigned short lA[3][8192];   // 3 x 16 KB (256 x 32)
    __shared__ __align__(16) unsigned short lB[3][4096];   // 3 x  8 KB (128 x 32)  => 72 KB

    int e, bm, bn, cnt;
    if (!merged_map<D_DIM / 128>(cntp, e, bm, bn, cnt)) return;

    const int* idx = idxb + e * IDXST;
    const float* wc = wcb + e * IDXST;
    const unsigned short* A = Hc + (size_t)e * CAPROWS * H_DIM;
    const unsigned short* Bmat = W2T + (size_t)e * D_DIM * H_DIM;
    const float* b2e = b2 + (size_t)e * D_DIM;
    float* OcE = Oc + (size_t)e * CAPROWS * D_DIM;

    const int tid = threadIdx.x;
    const int lane = tid & 63, wid = tid >> 6;
    const int wr = wid >> 1;        // 0..3  (M quarter: 64 rows)
    const int wcn = wid & 1;        // 0..1  (N half: 64 cols)
    const int fr = lane & 15, fq = lane >> 4;

    const int srow = tid >> 2;                                   // 0..127
    const int scol = (((tid & 3) ^ ((tid >> 3) & 3)) << 3);      // involution, 4 slots
    const unsigned short* Ab = A + (size_t)(bm * 256 + srow) * H_DIM + scol;
    const unsigned short* Bb = Bmat + (size_t)(bn * 128 + srow) * H_DIM + scol;

    const int soff = (fq ^ ((fr >> 1) & 3)) * 8;                 // read slot (ushort)

    f32x4 acc[4][4];
    #pragma unroll
    for (int m = 0; m < 4; ++m)
        #pragma unroll
        for (int n = 0; n < 4; ++n)
            acc[m][n] = (f32x4){0.f, 0.f, 0.f, 0.f};

    bf16x8 a[4], b[4];

    auto stageA = [&](int bf, int kt) {
        gload_lds16(Ab + kt * 32,                       &lA[bf][tid * 8]);
        gload_lds16(Ab + (size_t)128 * H_DIM + kt * 32, &lA[bf][4096 + tid * 8]);
    };
    auto stageB = [&](int bf, int kt) {
        gload_lds16(Bb + kt * 32, &lB[bf][tid * 8]);
    };

    stageA(0, 0); stageB(0, 0);
    stageA(1, 1); stageB(1, 1);
    VMC3();
    SBAR();

    const int NT = H_DIM / 32;   // 128
    int cb = 0;
    for (int t = 0; t < NT; ++t) {
        const int nb2 = (cb + 2 >= 3) ? cb - 1 : cb + 2;   // (t+2)%3
        #pragma unroll
        for (int mm = 0; mm < 4; ++mm) {
            const int r = wr * 64 + mm * 16 + fr;
            a[mm] = *(const bf16x8*)&lA[cb][r * 32 + soff];
        }
        #pragma unroll
        for (int n = 0; n < 4; ++n) {
            const int rB = wcn * 64 + n * 16 + fr;
            b[n] = *(const bf16x8*)&lB[cb][rB * 32 + soff];
        }
        if (t + 2 < NT) { stageA(nb2, t + 2); stageB(nb2, t + 2); }   // issue early (T14)
        LGKM0();
        __builtin_amdgcn_s_setprio(1);
        #pragma unroll
        for (int mm = 0; mm < 4; ++mm)
            #pragma unroll
            for (int n = 0; n < 4; ++n)
                acc[mm][n] = __builtin_amdgcn_mfma_f32_16x16x32_bf16(a[mm], b[n], acc[mm][n], 0, 0, 0);
        __builtin_amdgcn_s_setprio(0);
        if (t < NT - 2) { VMC3(); } else { VMC0(); }
        SBAR();
        cb = (cb == 2) ? 0 : cb + 1;
    }

    #pragma unroll
    for (int m = 0; m < 4; ++m) {
        const int rbase = bm * 256 + wr * 64 + m * 16 + fq * 4;
        #pragma unroll
        for (int n = 0; n < 4; ++n) {
            const int cn = bn * 128 + wcn * 64 + n * 16 + fr;
            const float bb = b2e[cn];
            #pragma unroll
            for (int j = 0; j < 4; ++j) {
                const int row = rbase + j;
                const float v = acc[m][n][j] + wc[row] * bb;   // padded rows: exact 0
                if (STORE == 1) {
                    OcE[(size_t)row * D_DIM + cn] = v;          // plain deterministic store
                } else if (row < cnt) {
                    const int tok = idx[row];
                    atomicAdd(&out[(size_t)tok * D_DIM + cn], v);
                }
            }
        }
    }
}

extern "C" void kernel_launch(void* const* d_in, const int* in_sizes, int n_in,
                              void* d_out, int out_size, void* d_ws, size_t ws_size,
                              hipStream_t stream) {
    const float* x  = (const float*)d_in[0];
    const float* Wg = (const float*)d_in[1];
    const float* bg = (const float*)d_in[2];
    const float* W1 = (const float*)d_in[3];
    const float* b1 = (const float*)d_in[4];
    const float* W2 = (const float*)d_in[5];
    const float* b2 = (const float*)d_in[6];
    float* out = (float*)d_out;
    char* ws = (char*)d_ws;

    const size_t off_w   = 0;                                           // wgt dense [T][E]: 256 KiB
    const size_t off_idx = 262144;                                      // idx: 8 x 8448 int
    const size_t off_wcc = 532480;                                      // wc:  8 x 8448 float
    const size_t off_cnt = 802816;                                      // cnt: 8 int
    const size_t off_pos = 806912;                                      // pos: 8 x 8192 int (256 KiB)
    const size_t off_x   = 2097152;                                     // Xbf16: 16 MiB
    const size_t off_w1  = off_x + (size_t)T_TOK * D_DIM * 2;           // W1T bf16 [E][H][D]
    const size_t off_w2  = off_w1 + (size_t)E_NUM * D_DIM * H_DIM * 2;  // W2T bf16 [E][D][H]
    const size_t off_h   = off_w2 + (size_t)E_NUM * D_DIM * H_DIM * 2;  // Hc bf16
    const size_t cap_h   = (size_t)E_NUM * CAPROWS * H_DIM * 2;         // 288 MiB
    const size_t off_oc  = off_h + cap_h;                               // Oc fp32 [E][CAPROWS][D]
    const size_t oc_sz   = (size_t)E_NUM * CAPROWS * D_DIM * 4;         // 144 MiB

    if (ws_size < off_h + cap_h) {
        sentinel_kernel<<<2048, 256, 0, stream>>>(out, (size_t)T_TOK * D_DIM);
        return;
    }
    const bool storePath = (ws_size >= off_oc + oc_sz);

    float* wgt = (float*)(ws + off_w);
    int* idxb  = (int*)(ws + off_idx);
    float* wcb = (float*)(ws + off_wcc);
    int* cntb  = (int*)(ws + off_cnt);
    int* posb  = (int*)(ws + off_pos);
    unsigned short* Xb  = (unsigned short*)(ws + off_x);
    unsigned short* W1T = (unsigned short*)(ws + off_w1);
    unsigned short* W2T = (unsigned short*)(ws + off_w2);
    unsigned short* Hc  = (unsigned short*)(ws + off_h);
    float* Oc = (float*)(ws + off_oc);

    gate_cvt_kernel<<<T_TOK / 4, 256, 0, stream>>>(x, Wg, bg, wgt, Xb);
    transpose_cvt<<<dim3(H_DIM / 64, D_DIM / 64, E_NUM), 256, 0, stream>>>(W1, W1T, D_DIM, H_DIM);
    transpose_cvt<<<dim3(D_DIM / 64, H_DIM / 64, E_NUM), 256, 0, stream>>>(W2, W2T, H_DIM, D_DIM);

    compact_kernel<<<E_NUM, 256, 0, stream>>>(wgt, idxb, wcb, cntb, posb);
    const int g1 = E_NUM * CAPBLK * (H_DIM / 128);   // 4608 worst case
    const int g2 = E_NUM * CAPBLK * (D_DIM / 128);   // 1152 worst case
    gemm1c<<<g1, 512, 0, stream>>>(Xb, W1T, Hc, b1, idxb, wcb, cntb);
    if (storePath) {
        gemm2c<1><<<g2, 512, 0, stream>>>(Hc, W2T, out, Oc, b2, idxb, wcb, cntb);
        reduce_kernel<<<(T_TOK * (D_DIM / 4)) / 256, 256, 0, stream>>>(
            (const float4*)Oc, posb, (float4*)out);
    } else {
        zero_kernel<<<2048, 256, 0, stream>>>((float4*)out, (size_t)T_TOK * D_DIM / 4);
        gemm2c<0><<<g2, 512, 0, stream>>>(Hc, W2T, out, Oc, b2, idxb, wcb, cntb);
    }
}